// Round 2
// baseline (6280.032 us; speedup 1.0000x reference)
//
#include <hip/hip_runtime.h>

// ---------------------------------------------------------------------------
// PolicyNetRSNNPB forward, MI355X/gfx950.  Round 11: 1 VALU inst per MAC.
// r10 passed (4.15 ms wall; k_rec ~3.7 ms unprofiled, 72% VALUBusy at 2
// waves/SIMD). The GEMM paid 3 VALU inst per (k,output): bfe + cvt + fmac —
// every consumer re-converted the same row bits 512x. This round converts
// each row's spike bits to floats ONCE (at staging) into a padded LDS
// buffer SF[2][16][516]; the GEMM inner loop is now ds_read_b128(w) +
// ds_read_b128(spkf broadcast) + 4x v_fmac per 4 k.
// Arithmetic FROZEN (numpy-fp32 emulation): identical fma chain — operands
// are exactly 0.0f/1.0f as before, ascending k per accumulator, K=512 split
// [0,384)+[384,512) merged by one fadd; elementwise single-rounded.
// Changes vs r10 (k_rec only):
//   (1) SF float staging (u16 LDS writes gone -> fewer bank conflicts;
//       stride-516 rows -> conflict-free GEMM reads; staging map
//       srow=tid&15, sjl=tid>>4 bounds write conflicts at 4-way).
//   (2) GEMM: fmaf(s4.[xyzw], w4.[xyzw], acc) — 1 VALU inst per k.
//   (3) LDS 129 KiB (WR 33K + WF 33K + SF 64.5K), 1 block/CU as before.
// Protocol unchanged: 1-based tags, parity-dbuf, ONE __syncthreads/step
// (reaching tp+2 staging requires all waves passed tp+1's barrier, which
// requires all finished reading SF[bp] at tp). k_prepT/k_xw/k_c3/k_scan/
// k_out and workspace layout unchanged.
// ---------------------------------------------------------------------------

typedef unsigned int       u32;
typedef unsigned short     u16;
typedef unsigned long long u64;
typedef unsigned char      u8;

#define TSTEPS 512
#define HIDDEN 512

// workspace layout (bytes) — unchanged from r7..r10.
#define XW_OFF    0ull
#define C3_OFF    0ull
#define MEM_OFF   33554432ull
#define SPKB_OFF  100663296ull
#define WT_OFF    109051904ull
#define WINT_OFF  109314048ull
#define RING_OFF  134217728ull
#define CNT_OFF   134742016ull
#define WS_NEED   (134742016ull + 4096ull)

#define QCHUNK 384

// ---------------------------------------------------------------------------
__global__ __launch_bounds__(256) void k_prepT(
    const float* __restrict__ Win,
    const float* __restrict__ Wmu, const float* __restrict__ Wlv,
    float* __restrict__ WinT, float* __restrict__ WT)
{
  const int idx = blockIdx.x * 256 + threadIdx.x;
  if (idx < 65536) {
    const int k = idx >> 9, j = idx & 511;
    WinT[idx] = Win[j * 128 + k];
  } else {
    const int i2 = idx - 65536;
    const int k = i2 >> 7, j = i2 & 127;
    WT[i2] = (j < 64) ? Wmu[j * 512 + k] : Wlv[(j - 64) * 512 + k];
  }
}

// ---------------------------------------------------------------------------
__global__ __launch_bounds__(256) void k_xw(
    const float* __restrict__ state, const float* __restrict__ target,
    const float* __restrict__ WinT, const float* __restrict__ b_in,
    float* __restrict__ XW)
{
  __shared__ float xs[16][129];
  const int tid  = threadIdx.x;
  const int row0 = blockIdx.x * 16;

  for (int e = tid; e < 2048; e += 256) {
    int r = e >> 7, k = e & 127;
    xs[r][k] = (k < 64) ? state[(row0 + r) * 64 + k]
                        : target[(row0 + r) * 64 + k - 64];
  }
  __syncthreads();

#pragma unroll
  for (int jh = 0; jh < 2; ++jh) {
    const int j = jh * 256 + tid;
    float acc[16];
#pragma unroll
    for (int r = 0; r < 16; ++r) acc[r] = 0.0f;
    for (int k = 0; k < 128; ++k) {
      const float wv = WinT[k * 512 + j];
#pragma unroll
      for (int r = 0; r < 16; ++r)
        acc[r] = __builtin_fmaf(xs[r][k], wv, acc[r]);
    }
    const float b = b_in[j];
#pragma unroll
    for (int r = 0; r < 16; ++r)
      XW[(row0 + r) * 512 + j] = __fadd_rn(acc[r], b);
  }
}

// ---------------------------------------------------------------------------
// k_rec: grid 256 = 8 groups x 32 members, block 512 = 8 waves (2/SIMD).
// Waves 0-3: rec GEMM+epilogue (tagged ring stores, 1-based tags).
// Waves 4-7: ff GEMM+epilogue (spkb32 history).
// Staging thread (srow=tid&15, sjl=tid>>4) polls 1 tagged ring word and
// converts its 16 spike bits to floats in SF[parity][srow][16*sjl..+16).
// GEMM: per 4 k, 2x ds_read_b128 + 4x v_fmac (spike floats broadcast to the
// 16 lanes sharing a row; weight reads 2-way/free; SF reads conflict-free).
// Sync: per-word tag polling + one __syncthreads per step (SF dbuf).
// ---------------------------------------------------------------------------
__global__ __launch_bounds__(512, 2) void k_rec(
    const float* __restrict__ XW,
    const float* __restrict__ Wrec, const float* __restrict__ Wff,
    const float* __restrict__ alpha_rec, const float* __restrict__ beta_rec,
    const float* __restrict__ b_rec,
    const float* __restrict__ b_ff, const float* __restrict__ alpha_ff,
    const float* __restrict__ beta_ff,
    u32* __restrict__ ring32, u32* __restrict__ spkb32)
{
  __shared__ float WR[16 * 516];      // 33024 B
  __shared__ float WF[16 * 516];      // 33024 B
  __shared__ float SF[2][16][516];    // 66048 B  spike floats, parity dbuf

  const int tid  = threadIdx.x;
  const int g    = blockIdx.x & 7;
  const int c    = blockIdx.x >> 3;          // 0..31 (16 channels each)
  const int n0   = g * 16;
  const int wv   = tid >> 6;                 // 0..7
  const int lane = tid & 63;
  const int ch   = lane & 15;                // channel within member
  const int rloc = lane >> 4;                // 0..3
  const int row  = (wv & 3) * 4 + rloc;      // 0..15 within group
  const bool isFF = (wv >= 4);
  const int jj   = c * 16 + ch;              // global hidden unit

  for (int it = tid; it < 2048; it += 512) {
    const int r16 = it >> 7, k4 = (it & 127) * 4;
    *(float4*)(WR + r16 * 516 + k4) = *(const float4*)(Wrec + (c * 16 + r16) * 512 + k4);
    *(float4*)(WF + r16 * 516 + k4) = *(const float4*)(Wff  + (c * 16 + r16) * 512 + k4);
  }

  float coA, coB, coC;
  if (!isFF) { coA = alpha_rec[jj]; coB = beta_rec[jj]; coC = b_rec[jj]; }
  else       { coA = alpha_ff[jj];  coB = beta_ff[jj];  coC = b_ff[jj]; }

  float syn = 0.f, mem = 0.f, spk = 0.f, xw = 0.f;

  const float* wp = (isFF ? WF : WR) + ch * 516;
  const int srow = tid & 15;    // staged row   (maps wave lanes across rows:
  const int sjl  = tid >> 4;    // staged word   bounds LDS write conflicts)

  __syncthreads();  // weights ready

  for (int tp = 0; tp <= TSTEPS; ++tp) {
    // XW reused for both repeats of a t_step (reference passes the same x
    // to both neuron_step calls) — load once per pair, value-identical.
    if (!isFF && tp < TSTEPS && !(tp & 1))
      xw = XW[((tp >> 1) * 128 + n0 + row) * 512 + jj];

    float SA = 0.f;

    if (tp > 0) {
      const int bp = (tp - 1) & 1;
      { // stage spike bits of step tp-1: poll 1 tagged word (tag = tp),
        // convert 16 bits -> 16 floats into SF[bp].
        const u32 expct = (u32)tp;
        const u32* src = ring32 + (bp * 128 + n0 + srow) * 32 + sjl;
        u32 m = __hip_atomic_load(src, __ATOMIC_RELAXED, __HIP_MEMORY_SCOPE_AGENT);
        while ((m >> 16) != expct) {
          __builtin_amdgcn_s_sleep(1);
          m = __hip_atomic_load(src, __ATOMIC_RELAXED, __HIP_MEMORY_SCOPE_AGENT);
        }
        float f[16];
#pragma unroll
        for (int i = 0; i < 16; ++i) f[i] = (float)((m >> i) & 1u);
        float* d = &SF[bp][srow][sjl * 16];
        *(float4*)(d +  0) = make_float4(f[0],  f[1],  f[2],  f[3]);
        *(float4*)(d +  4) = make_float4(f[4],  f[5],  f[6],  f[7]);
        *(float4*)(d +  8) = make_float4(f[8],  f[9],  f[10], f[11]);
        *(float4*)(d + 12) = make_float4(f[12], f[13], f[14], f[15]);
      }
      __syncthreads();   // SF[bp] complete; bounds skew for dbuf reuse

      if (isFF || tp < TSTEPS) {
        // BLAS-faithful GEMM: seq-FMA ascending k, chunk split at kb=12.
        // Spike floats are exactly 0.0f/1.0f -> identical fma operands.
        const float* sp = &SF[bp][row][0];
        float aA = 0.f, aB = 0.f;
#pragma unroll
        for (int kb = 0; kb < 12; ++kb) {
#pragma unroll
          for (int k4 = 0; k4 < 32; k4 += 4) {
            const float4 w4 = *(const float4*)(wp + kb * 32 + k4);
            const float4 s4 = *(const float4*)(sp + kb * 32 + k4);
            aA = __builtin_fmaf(s4.x, w4.x, aA);
            aA = __builtin_fmaf(s4.y, w4.y, aA);
            aA = __builtin_fmaf(s4.z, w4.z, aA);
            aA = __builtin_fmaf(s4.w, w4.w, aA);
          }
        }
#pragma unroll
        for (int kb = 12; kb < 16; ++kb) {
#pragma unroll
          for (int k4 = 0; k4 < 32; k4 += 4) {
            const float4 w4 = *(const float4*)(wp + kb * 32 + k4);
            const float4 s4 = *(const float4*)(sp + kb * 32 + k4);
            aB = __builtin_fmaf(s4.x, w4.x, aB);
            aB = __builtin_fmaf(s4.y, w4.y, aB);
            aB = __builtin_fmaf(s4.z, w4.z, aB);
            aB = __builtin_fmaf(s4.w, w4.w, aB);
          }
        }
        SA = __fadd_rn(aA, aB);
      }
    }

    if (isFF) {
      if (tp > 0) {
        // ff epilogue for step tp-1
        float curf = __fadd_rn(SA, coC);
        syn = __fadd_rn(__fmul_rn(coA, syn), curf);
        mem = __fsub_rn(__fadd_rn(__fmul_rn(coB, mem), syn), spk);
        spk = (mem > 1.0f) ? 1.0f : 0.0f;
        const u64 B = __ballot(spk != 0.f);
        if (ch == 0) {
          spkb32[((u64)(tp - 1) * 128 + n0 + row) * 32 + c] =
              (u32)((B >> (16 * rloc)) & 0xFFFFull);
        }
      }
    } else {
      if (tp < TSTEPS) {
        // rec epilogue for step tp; tagged ring store (tag = tp+1, 1-based)
        float cur = __fadd_rn(__fadd_rn(xw, SA), coC);
        syn = __fadd_rn(__fmul_rn(coA, syn), cur);
        mem = __fsub_rn(__fadd_rn(__fmul_rn(coB, mem), syn), spk);
        spk = (mem > 1.0f) ? 1.0f : 0.0f;
        const u64 B = __ballot(spk != 0.f);
        if (ch == 0) {
          const u32 tag = ((u32)(tp + 1)) << 16;
          __hip_atomic_store(ring32 + ((tp & 1) * 128 + n0 + row) * 32 + c,
                             tag | (u32)((B >> (16 * rloc)) & 0xFFFFull),
                             __ATOMIC_RELAXED, __HIP_MEMORY_SCOPE_AGENT);
        }
      }
    }
    // no end-of-step barrier: SF is double-buffered; the pre-GEMM barrier
    // bounds inter-wave skew to one step.
  }
}

// ---------------------------------------------------------------------------
__global__ __launch_bounds__(256) void k_c3(
    const u32* __restrict__ spkb32, const float* __restrict__ WT,
    const float* __restrict__ bmu, const float* __restrict__ blv,
    float* __restrict__ c3)
{
  __shared__ u32 Bc[32][32];
  const int tid  = threadIdx.x;
  const int rows0 = blockIdx.x * 32;

  for (int it = tid; it < 1024; it += 256)
    ((u32*)Bc)[it] = spkb32[(u64)rows0 * 32 + it];
  __syncthreads();

  const int j  = tid & 127;
  const int rh = tid >> 7;
  const float bias = (j < 64) ? bmu[j] : blv[j - 64];

  float accA[16], accB[16];
#pragma unroll
  for (int r = 0; r < 16; ++r) { accA[r] = 0.f; accB[r] = 0.f; }

  for (int m = 0; m < 24; ++m) {
    u32 wrow[16];
#pragma unroll
    for (int r = 0; r < 16; ++r) wrow[r] = Bc[rh * 16 + r][m];
    const float* wpp = WT + (m * 16) * 128 + j;
#pragma unroll
    for (int kk = 0; kk < 16; ++kk) {
      const float wvv = wpp[kk * 128];
#pragma unroll
      for (int r = 0; r < 16; ++r) {
        const float b = (float)((wrow[r] >> kk) & 1u);
        accA[r] = __builtin_fmaf(b, wvv, accA[r]);
      }
    }
  }
  for (int m = 24; m < 32; ++m) {
    u32 wrow[16];
#pragma unroll
    for (int r = 0; r < 16; ++r) wrow[r] = Bc[rh * 16 + r][m];
    const float* wpp = WT + (m * 16) * 128 + j;
#pragma unroll
    for (int kk = 0; kk < 16; ++kk) {
      const float wvv = wpp[kk * 128];
#pragma unroll
      for (int r = 0; r < 16; ++r) {
        const float b = (float)((wrow[r] >> kk) & 1u);
        accB[r] = __builtin_fmaf(b, wvv, accB[r]);
      }
    }
  }

#pragma unroll
  for (int r = 0; r < 16; ++r)
    c3[(u64)(rows0 + rh * 16 + r) * 128 + j] =
        __fadd_rn(__fadd_rn(accA[r], accB[r]), bias);
}

// ---------------------------------------------------------------------------
__global__ __launch_bounds__(256) void k_scan(
    const float* __restrict__ c3,
    const float* __restrict__ beta_mu, const float* __restrict__ beta_lv,
    float* __restrict__ Mem)
{
  const int tid = blockIdx.x * 256 + threadIdx.x;
  const int n = tid >> 7, ap = tid & 127;
  const float beta = (ap < 64) ? beta_mu[ap] : beta_lv[ap - 64];
  const float* src = c3 + n * 128 + ap;
  float* dst = Mem + n * 128 + ap;
  float mem = 0.0f;
  for (int t = 0; t < 512; ++t) {
    mem = __fadd_rn(__fmul_rn(beta, mem), src[(u64)t * 16384]);
    dst[(u64)t * 16384] = mem;
  }
}

// ---------------------------------------------------------------------------
__global__ __launch_bounds__(256) void k_out(
    const float* __restrict__ Mem,
    const float* __restrict__ Wmu_out, const float* __restrict__ Wlv_out,
    float* __restrict__ out)
{
  const int tid = blockIdx.x * 256 + threadIdx.x;
  const int a = tid & 7;
  const int n = (tid >> 3) & 127;
  const int t = (tid >> 10) & 255;
  const int kind = tid >> 18;
  const float* wv = ((kind == 0) ? Wmu_out : Wlv_out) + a * 64;
  const float* s0 = Mem + ((u64)(2 * t) * 128 + n) * 128 + kind * 64;
  const float* s1 = Mem + ((u64)(2 * t + 1) * 128 + n) * 128 + kind * 64;
  float mu0 = 0.0f, mu1 = 0.0f;
#pragma unroll 8
  for (int q = 0; q < 64; ++q) mu0 = __builtin_fmaf(s0[q], wv[q], mu0);
#pragma unroll 8
  for (int q = 0; q < 64; ++q) mu1 = __builtin_fmaf(s1[q], wv[q], mu1);
  out[tid] = __fmul_rn(__fadd_rn(mu0, mu1), 0.5f);
}

// ---------------------------------------------------------------------------
extern "C" void kernel_launch(void* const* d_in, const int* in_sizes, int n_in,
                              void* d_out, int out_size, void* d_ws, size_t ws_size,
                              hipStream_t stream) {
  (void)in_sizes; (void)n_in; (void)out_size;
  if (ws_size < WS_NEED) return;

  const float* state     = (const float*)d_in[0];
  const float* target    = (const float*)d_in[1];
  const float* W_rec_in  = (const float*)d_in[2];
  const float* b_rec_in  = (const float*)d_in[3];
  const float* W_rec     = (const float*)d_in[4];
  const float* b_rec     = (const float*)d_in[5];
  const float* alpha_rec = (const float*)d_in[6];
  const float* beta_rec  = (const float*)d_in[7];
  const float* W_ff_in   = (const float*)d_in[8];
  const float* b_ff_in   = (const float*)d_in[9];
  const float* alpha_ff  = (const float*)d_in[10];
  const float* beta_ff   = (const float*)d_in[11];
  const float* W_mu_in   = (const float*)d_in[12];
  const float* b_mu_in   = (const float*)d_in[13];
  const float* beta_mu   = (const float*)d_in[14];
  const float* W_mu_out  = (const float*)d_in[15];
  const float* W_lv_in   = (const float*)d_in[16];
  const float* b_lv_in   = (const float*)d_in[17];
  const float* beta_lv   = (const float*)d_in[18];
  const float* W_lv_out  = (const float*)d_in[19];

  char* ws = (char*)d_ws;
  float* XW    = (float*)(ws + XW_OFF);
  float* c3    = (float*)(ws + C3_OFF);
  float* Mem   = (float*)(ws + MEM_OFF);
  u32*   spkb32= (u32*)  (ws + SPKB_OFF);
  float* WT    = (float*)(ws + WT_OFF);
  float* WinT  = (float*)(ws + WINT_OFF);
  u32*   ring32= (u32*)  (ws + RING_OFF);

  hipLaunchKernelGGL(k_prepT, dim3(512), dim3(256), 0, stream,
                     W_rec_in, W_mu_in, W_lv_in, WinT, WT);
  hipLaunchKernelGGL(k_xw, dim3(2048), dim3(256), 0, stream,
                     state, target, WinT, b_rec_in, XW);
  hipLaunchKernelGGL(k_rec, dim3(256), dim3(512), 0, stream,
                     XW, W_rec, W_ff_in,
                     alpha_rec, beta_rec, b_rec,
                     b_ff_in, alpha_ff, beta_ff, ring32, spkb32);
  hipLaunchKernelGGL(k_c3, dim3(2048), dim3(256), 0, stream,
                     spkb32, WT, b_mu_in, b_lv_in, c3);
  hipLaunchKernelGGL(k_scan, dim3(64), dim3(256), 0, stream,
                     c3, beta_mu, beta_lv, Mem);
  hipLaunchKernelGGL(k_out, dim3(2048), dim3(256), 0, stream,
                     Mem, W_mu_out, W_lv_out, (float*)d_out);
}

// Round 3
// 5416.803 us; speedup vs baseline: 1.1594x; 1.1594x over previous
//
#include <hip/hip_runtime.h>

// ---------------------------------------------------------------------------
// PolicyNetRSNNPB forward, MI355X/gfx950.  Round 12: zero-memory inner loop.
// r11 regressed (6.28 ms): VALUBusy 26% but LDS pipe saturated — 2 ds_read_b128
// per 4 MACs = ~24K cy/CU/step (matches 11.5 us/step). Proven twice: any
// operand streamed per-lane from LDS costs >=8-12K cy/CU/step at this blocking.
// This round removes BOTH operands from the memory pipes:
//   * RELAYOUT: wave = one hidden unit j (uniform) x 64 batch rows (lane=row).
//     256 blocks = {128 rec + 128 ff} x (64 j-octets x 2 rowgroups), 8 waves.
//   * Weights: distributed in wave VGPRs (8/lane, loaded once); fetched per-k
//     with v_readlane (compile-time lane) -> no LDS/VMEM in the MAC loop.
//   * Spikes: row bits in 16 VGPRs; per k: msk=sbfe(bits,k,1); ws=msk&w;
//     acc=fadd(acc,ws). BIT-EXACT to frozen chain: bit=1 -> fadd(acc,w) ==
//     fma(1,w,acc); bit=0 -> acc+(+0) == fma(0,w,acc) (acc never -0 from +0
//     start under RN). Ascending k, 384-split, single fadd merge: unchanged.
//   * Ring: NO-REUSE tagged ring (tag24|mask8 per (t, j-octet, row)), 16 MiB
//     in the dead [64MiB,80MiB) hole. rec never waits on ff; no slot reuse;
//     memset-zero tags never match (expected tags >= 1).
//   * Per step: 8 coalesced atomic loads/wave -> LDS byte tile -> bar1 ->
//     4x ds_read_b128 (64B bits) -> 512x(readlane+bfe+and+add) -> epilogue ->
//     bar2 -> wave0 packs 8 spike bytes -> 1 coalesced store.
// k_xw now stores XW TRANSPOSED [(t2*512+j)*128+n] (consumer lane=n coalesced).
// k_c3 adapted to byte-packed spike history spkb8[(t*64+c8)*128+n].
// All fp ops/order identical to r10/r11 (numpy-fp32 emulation, frozen).
// ---------------------------------------------------------------------------

typedef unsigned int       u32;
typedef unsigned short     u16;
typedef unsigned long long u64;
typedef unsigned char      u8;

#define TSTEPS 512
#define HIDDEN 512

// workspace layout (bytes).
//   [0,64Mi)   XW transposed (dead after k_rec; c3 [0,32Mi) + Mem [32Mi,64Mi))
//   [64,80Mi)  ring32 (no-reuse tagged spike ring, k_rec only)
//   [96,100Mi) spkb8 (ff spike history, bytes)
//   [104Mi..)  WT, WinT (unchanged)
#define XW_OFF    0ull
#define C3_OFF    0ull
#define MEM_OFF   33554432ull
#define RINGN_OFF 67108864ull
#define SPKB_OFF  100663296ull
#define WT_OFF    109051904ull
#define WINT_OFF  109314048ull
#define WS_NEED   (134742016ull + 4096ull)

// ---------------------------------------------------------------------------
__global__ __launch_bounds__(256) void k_prepT(
    const float* __restrict__ Win,
    const float* __restrict__ Wmu, const float* __restrict__ Wlv,
    float* __restrict__ WinT, float* __restrict__ WT)
{
  const int idx = blockIdx.x * 256 + threadIdx.x;
  if (idx < 65536) {
    const int k = idx >> 9, j = idx & 511;
    WinT[idx] = Win[j * 128 + k];
  } else {
    const int i2 = idx - 65536;
    const int k = i2 >> 7, j = i2 & 127;
    WT[i2] = (j < 64) ? Wmu[j * 512 + k] : Wlv[(j - 64) * 512 + k];
  }
}

// ---------------------------------------------------------------------------
// k_xw: unchanged GEMM, TRANSPOSED store: XWT[(t2*512 + j)*128 + n].
// Block covers 16 consecutive global rows (same t2, consecutive n).
// ---------------------------------------------------------------------------
__global__ __launch_bounds__(256) void k_xw(
    const float* __restrict__ state, const float* __restrict__ target,
    const float* __restrict__ WinT, const float* __restrict__ b_in,
    float* __restrict__ XWT)
{
  __shared__ float xs[16][129];
  const int tid  = threadIdx.x;
  const int row0 = blockIdx.x * 16;

  for (int e = tid; e < 2048; e += 256) {
    int r = e >> 7, k = e & 127;
    xs[r][k] = (k < 64) ? state[(row0 + r) * 64 + k]
                        : target[(row0 + r) * 64 + k - 64];
  }
  __syncthreads();

  const int t2 = row0 >> 7;
  const int n0 = row0 & 127;

#pragma unroll
  for (int jh = 0; jh < 2; ++jh) {
    const int j = jh * 256 + tid;
    float acc[16];
#pragma unroll
    for (int r = 0; r < 16; ++r) acc[r] = 0.0f;
    for (int k = 0; k < 128; ++k) {
      const float wv = WinT[k * 512 + j];
#pragma unroll
      for (int r = 0; r < 16; ++r)
        acc[r] = __builtin_fmaf(xs[r][k], wv, acc[r]);
    }
    const float b = b_in[j];
    float* dst = XWT + ((u64)t2 * 512 + j) * 128 + n0;
#pragma unroll
    for (int r4 = 0; r4 < 4; ++r4) {
      float4 o;
      o.x = __fadd_rn(acc[r4 * 4 + 0], b);
      o.y = __fadd_rn(acc[r4 * 4 + 1], b);
      o.z = __fadd_rn(acc[r4 * 4 + 2], b);
      o.w = __fadd_rn(acc[r4 * 4 + 3], b);
      *(float4*)(dst + r4 * 4) = o;
    }
  }
}

// ---------------------------------------------------------------------------
// k_rec: grid 256 x 512 threads (8 waves, 2/SIMD).
// blockIdx < 128: REC blocks; >= 128: FF blocks (homogeneous blocks).
// Block (role, cb, R): j in [8cb, 8cb+8) (wave w -> j = 8cb+w),
// rows gn = R*64 + lane.  Loop i = 0..511:
//   rec: step i, polls ring slot i-1 (tag i), stores slot i (tag i+1).
//   ff:  step i, polls ring slot i   (tag i+1), stores spkb8[i].
// ---------------------------------------------------------------------------
__global__ __launch_bounds__(512, 2) void k_rec(
    const float* __restrict__ XWT,
    const float* __restrict__ Wrec, const float* __restrict__ Wff,
    const float* __restrict__ alpha_rec, const float* __restrict__ beta_rec,
    const float* __restrict__ b_rec,
    const float* __restrict__ b_ff, const float* __restrict__ alpha_ff,
    const float* __restrict__ beta_ff,
    u32* __restrict__ ring32, u8* __restrict__ spkb8)
{
  __shared__ __align__(16) u8 MB[64][80];  // [row][c8 byte], pad 80
  __shared__ __align__(8)  u8 SP[64][8];   // [row][wave] spike bytes

  const int tid  = threadIdx.x;
  const int w    = tid >> 6;          // wave 0..7  -> j-offset
  const int n    = tid & 63;          // lane       -> row within rowgroup
  const int bb   = blockIdx.x & 127;
  const bool isFF = (blockIdx.x >= 128);
  const int cb   = bb >> 1;           // j-octet 0..63
  const int R    = bb & 1;            // rowgroup
  const int jj   = cb * 8 + w;        // hidden unit (wave-uniform)
  const int gn   = R * 64 + n;        // global batch row

  // distributed weight row: lane holds W[jj][8n .. 8n+8)
  const float* Wbase = (isFF ? Wff : Wrec) + (u64)jj * 512 + n * 8;
  const float4 wv0 = *(const float4*)(Wbase + 0);
  const float4 wv1 = *(const float4*)(Wbase + 4);
  int wd[8];
  wd[0] = __float_as_int(wv0.x); wd[1] = __float_as_int(wv0.y);
  wd[2] = __float_as_int(wv0.z); wd[3] = __float_as_int(wv0.w);
  wd[4] = __float_as_int(wv1.x); wd[5] = __float_as_int(wv1.y);
  wd[6] = __float_as_int(wv1.z); wd[7] = __float_as_int(wv1.w);

  const float coA = isFF ? alpha_ff[jj] : alpha_rec[jj];
  const float coB = isFF ? beta_ff[jj]  : beta_rec[jj];
  const float coC = isFF ? b_ff[jj]     : b_rec[jj];

  float syn = 0.f, mem = 0.f, spk = 0.f, xw = 0.f;

#pragma unroll 1
  for (int i = 0; i < TSTEPS; ++i) {
    // keep wd loop-variant so 512 readlanes can't be hoisted out of the step loop
    asm volatile("" : "+v"(wd[0]), "+v"(wd[1]), "+v"(wd[2]), "+v"(wd[3]),
                      "+v"(wd[4]), "+v"(wd[5]), "+v"(wd[6]), "+v"(wd[7]));

    if (!isFF && !(i & 1))
      xw = XWT[((u64)(i >> 1) * 512 + jj) * 128 + gn];

    const int slot  = isFF ? i : (i - 1);
    const u32 expct = isFF ? (u32)(i + 1) : (u32)i;

    if (expct) {
      // poll 8 tagged words: c8 = 8w..8w+7, own row gn (coalesced per instr)
      const u32* src = ring32 + ((u64)slot * 64 + 8 * w) * 128 + gn;
      u32 vv[8];
      for (;;) {
        u32 bad = 0;
#pragma unroll
        for (int s = 0; s < 8; ++s) {
          vv[s] = __hip_atomic_load(src + s * 128, __ATOMIC_RELAXED,
                                    __HIP_MEMORY_SCOPE_AGENT);
          bad |= (vv[s] >> 8) ^ expct;
        }
        if (__all(bad == 0)) break;
        __builtin_amdgcn_s_sleep(1);
      }
      u64 mb = 0;
#pragma unroll
      for (int s = 0; s < 8; ++s) mb |= (u64)(vv[s] & 0xFFu) << (8 * s);
      *(u64*)&MB[n][8 * w] = mb;
    }
    __syncthreads();  // bar1: MB complete (prev-iter MAC reads fenced by bar2)

    float SA = 0.f;
    if (expct) {
      // own row's 512 spike bits: 64 bytes -> 16 VGPRs
      const uint4* bq = (const uint4*)&MB[n][0];
      const uint4 q0 = bq[0], q1 = bq[1], q2 = bq[2], q3 = bq[3];
      u32 b[16] = { q0.x, q0.y, q0.z, q0.w, q1.x, q1.y, q1.z, q1.w,
                    q2.x, q2.y, q2.z, q2.w, q3.x, q3.y, q3.z, q3.w };
      float aA = 0.f, aB = 0.f;
      // BLAS-faithful: seq-FMA-equivalent ascending k, chunk split at 384.
#pragma unroll
      for (int k = 0; k < 512; ++k) {
        const int wq  = __builtin_amdgcn_readlane(wd[k & 7], k >> 3);
        const int msk = (int)(b[k >> 5] << (31 - (k & 31))) >> 31;  // 0 / -1
        const float ws = __int_as_float(msk & wq);                  // w or +0
        if (k < 384) aA = __fadd_rn(aA, ws);
        else         aB = __fadd_rn(aB, ws);
      }
      SA = __fadd_rn(aA, aB);
    }

    // epilogue (single-rounded, identical op sequence to r10/r11)
    const float cur = isFF ? __fadd_rn(SA, coC)
                           : __fadd_rn(__fadd_rn(xw, SA), coC);
    syn = __fadd_rn(__fmul_rn(coA, syn), cur);
    mem = __fsub_rn(__fadd_rn(__fmul_rn(coB, mem), syn), spk);
    spk = (mem > 1.0f) ? 1.0f : 0.0f;
    SP[n][w] = (u8)(spk != 0.f);

    __syncthreads();  // bar2: SP complete; also fences MB reuse next iter

    if (w == 0) {
      const u64 sv  = *(const u64*)&SP[n][0];
      const u32 lo4 = ((u32)sv         * 0x01020408u) >> 24;  // bits w=0..3
      const u32 hi4 = ((u32)(sv >> 32) * 0x01020408u) >> 24;  // bits w=4..7
      const u32 mask = lo4 | (hi4 << 4);
      if (!isFF) {
        __hip_atomic_store(ring32 + ((u64)i * 64 + cb) * 128 + gn,
                           ((u32)(i + 1) << 8) | mask,
                           __ATOMIC_RELAXED, __HIP_MEMORY_SCOPE_AGENT);
      } else {
        spkb8[((u64)i * 64 + cb) * 128 + gn] = (u8)mask;
      }
    }
  }
}

// ---------------------------------------------------------------------------
// k_c3: spk_f history (bytes, c8-major) @ W_mu/W_lv readout, + bias.
// Block: 32 consecutive global rows (same t, n0..n0+32) x 128 outputs.
// ---------------------------------------------------------------------------
__global__ __launch_bounds__(256) void k_c3(
    const u8* __restrict__ spkb8, const float* __restrict__ WT,
    const float* __restrict__ bmu, const float* __restrict__ blv,
    float* __restrict__ c3)
{
  __shared__ __align__(8) u8 Bc[64][40];  // [c8][n-local 32, pad 40]
  const int tid   = threadIdx.x;
  const int rows0 = blockIdx.x * 32;
  const int t     = rows0 >> 7;
  const int n0    = rows0 & 127;

  {
    const int c8 = tid >> 2, g = tid & 3;
    const u64 vv = *(const u64*)(spkb8 + ((u64)t * 64 + c8) * 128 + n0 + 8 * g);
    *(u64*)&Bc[c8][8 * g] = vv;
  }
  __syncthreads();

  const int j  = tid & 127;
  const int rh = tid >> 7;
  const float bias = (j < 64) ? bmu[j] : blv[j - 64];

  float accA[16], accB[16];
#pragma unroll
  for (int r = 0; r < 16; ++r) { accA[r] = 0.f; accB[r] = 0.f; }

  for (int m = 0; m < 48; ++m) {   // k = 8m+kk < 384
    u32 w32[4];
#pragma unroll
    for (int q = 0; q < 4; ++q) w32[q] = *(const u32*)&Bc[m][rh * 16 + 4 * q];
    const float* wpp = WT + (m * 8) * 128 + j;
#pragma unroll
    for (int kk = 0; kk < 8; ++kk) {
      const float wvv = wpp[kk * 128];
#pragma unroll
      for (int r = 0; r < 16; ++r) {
        const float b = (float)((w32[r >> 2] >> (((r & 3) << 3) + kk)) & 1u);
        accA[r] = __builtin_fmaf(b, wvv, accA[r]);
      }
    }
  }
  for (int m = 48; m < 64; ++m) {  // k >= 384
    u32 w32[4];
#pragma unroll
    for (int q = 0; q < 4; ++q) w32[q] = *(const u32*)&Bc[m][rh * 16 + 4 * q];
    const float* wpp = WT + (m * 8) * 128 + j;
#pragma unroll
    for (int kk = 0; kk < 8; ++kk) {
      const float wvv = wpp[kk * 128];
#pragma unroll
      for (int r = 0; r < 16; ++r) {
        const float b = (float)((w32[r >> 2] >> (((r & 3) << 3) + kk)) & 1u);
        accB[r] = __builtin_fmaf(b, wvv, accB[r]);
      }
    }
  }

#pragma unroll
  for (int r = 0; r < 16; ++r)
    c3[(u64)(rows0 + rh * 16 + r) * 128 + j] =
        __fadd_rn(__fadd_rn(accA[r], accB[r]), bias);
}

// ---------------------------------------------------------------------------
__global__ __launch_bounds__(256) void k_scan(
    const float* __restrict__ c3,
    const float* __restrict__ beta_mu, const float* __restrict__ beta_lv,
    float* __restrict__ Mem)
{
  const int tid = blockIdx.x * 256 + threadIdx.x;
  const int n = tid >> 7, ap = tid & 127;
  const float beta = (ap < 64) ? beta_mu[ap] : beta_lv[ap - 64];
  const float* src = c3 + n * 128 + ap;
  float* dst = Mem + n * 128 + ap;
  float mem = 0.0f;
  for (int t = 0; t < 512; ++t) {
    mem = __fadd_rn(__fmul_rn(beta, mem), src[(u64)t * 16384]);
    dst[(u64)t * 16384] = mem;
  }
}

// ---------------------------------------------------------------------------
__global__ __launch_bounds__(256) void k_out(
    const float* __restrict__ Mem,
    const float* __restrict__ Wmu_out, const float* __restrict__ Wlv_out,
    float* __restrict__ out)
{
  const int tid = blockIdx.x * 256 + threadIdx.x;
  const int a = tid & 7;
  const int n = (tid >> 3) & 127;
  const int t = (tid >> 10) & 255;
  const int kind = tid >> 18;
  const float* wv = ((kind == 0) ? Wmu_out : Wlv_out) + a * 64;
  const float* s0 = Mem + ((u64)(2 * t) * 128 + n) * 128 + kind * 64;
  const float* s1 = Mem + ((u64)(2 * t + 1) * 128 + n) * 128 + kind * 64;
  float mu0 = 0.0f, mu1 = 0.0f;
#pragma unroll 8
  for (int q = 0; q < 64; ++q) mu0 = __builtin_fmaf(s0[q], wv[q], mu0);
#pragma unroll 8
  for (int q = 0; q < 64; ++q) mu1 = __builtin_fmaf(s1[q], wv[q], mu1);
  out[tid] = __fmul_rn(__fadd_rn(mu0, mu1), 0.5f);
}

// ---------------------------------------------------------------------------
extern "C" void kernel_launch(void* const* d_in, const int* in_sizes, int n_in,
                              void* d_out, int out_size, void* d_ws, size_t ws_size,
                              hipStream_t stream) {
  (void)in_sizes; (void)n_in; (void)out_size;
  if (ws_size < WS_NEED) return;

  const float* state     = (const float*)d_in[0];
  const float* target    = (const float*)d_in[1];
  const float* W_rec_in  = (const float*)d_in[2];
  const float* b_rec_in  = (const float*)d_in[3];
  const float* W_rec     = (const float*)d_in[4];
  const float* b_rec     = (const float*)d_in[5];
  const float* alpha_rec = (const float*)d_in[6];
  const float* beta_rec  = (const float*)d_in[7];
  const float* W_ff_in   = (const float*)d_in[8];
  const float* b_ff_in   = (const float*)d_in[9];
  const float* alpha_ff  = (const float*)d_in[10];
  const float* beta_ff   = (const float*)d_in[11];
  const float* W_mu_in   = (const float*)d_in[12];
  const float* b_mu_in   = (const float*)d_in[13];
  const float* beta_mu   = (const float*)d_in[14];
  const float* W_mu_out  = (const float*)d_in[15];
  const float* W_lv_in   = (const float*)d_in[16];
  const float* b_lv_in   = (const float*)d_in[17];
  const float* beta_lv   = (const float*)d_in[18];
  const float* W_lv_out  = (const float*)d_in[19];

  char* ws = (char*)d_ws;
  float* XWT   = (float*)(ws + XW_OFF);
  float* c3    = (float*)(ws + C3_OFF);
  float* Mem   = (float*)(ws + MEM_OFF);
  u32*   ring32= (u32*)  (ws + RINGN_OFF);
  u8*    spkb8 = (u8*)   (ws + SPKB_OFF);
  float* WT    = (float*)(ws + WT_OFF);
  float* WinT  = (float*)(ws + WINT_OFF);

  hipLaunchKernelGGL(k_prepT, dim3(512), dim3(256), 0, stream,
                     W_rec_in, W_mu_in, W_lv_in, WinT, WT);
  hipLaunchKernelGGL(k_xw, dim3(2048), dim3(256), 0, stream,
                     state, target, WinT, b_rec_in, XWT);
  hipLaunchKernelGGL(k_rec, dim3(256), dim3(512), 0, stream,
                     XWT, W_rec, W_ff_in,
                     alpha_rec, beta_rec, b_rec,
                     b_ff_in, alpha_ff, beta_ff, ring32, spkb8);
  hipLaunchKernelGGL(k_c3, dim3(2048), dim3(256), 0, stream,
                     spkb8, WT, b_mu_in, b_lv_in, c3);
  hipLaunchKernelGGL(k_scan, dim3(64), dim3(256), 0, stream,
                     c3, beta_mu, beta_lv, Mem);
  hipLaunchKernelGGL(k_out, dim3(2048), dim3(256), 0, stream,
                     Mem, W_mu_out, W_lv_out, (float*)d_out);
}

// Round 4
// 5146.664 us; speedup vs baseline: 1.2202x; 1.0525x over previous
//
#include <hip/hip_runtime.h>

// ---------------------------------------------------------------------------
// PolicyNetRSNNPB forward, MI355X/gfx950.  Round 13: 3 VALU/MAC + forced
// 1 block/CU.
// r12: wall 5417 us, k_rec ~9.7 us/step profiled @ VALUBusy 85%, LDS fixed
// (conflicts 3e8->3.8e7). Gap vs 4-inst model (3.4 us) diagnosed as:
//   (a) CO-RESIDENCY: LDS 5.6KB + VGPR 36 allowed 2 blocks/CU on SOME CUs
//       (dispatch undefined). Every step is all-to-all, so one doubled CU
//       gates all 256 blocks -> ~2x. FIX: LDS pad to 82.9KB forces exactly
//       1 block/CU (precedent: r11 ran 132KB x 256 blocks fine).
//   (b) v_readlane cost 1 VALU/MAC + SGPR-write hazard. The weight is
//       wave-uniform -> move it to the SMEM pipe: jj forced scalar via
//       readfirstlane, unrolled Wrow[k] loads become s_load (co-issue).
//       Inner loop: v_bfe_i32 + v_and_b32(s_w) + v_add_f32 = 3 VALU/MAC.
// Arithmetic FROZEN (numpy-fp32 emulation), BIT-EXACT to r10/r11/r12:
//   bit=1 -> fadd(acc, w) == fma(1,w,acc); bit=0 -> fadd(acc, +0) == acc
//   (acc starts +0, never -0 under RN). Ascending k per accumulator,
//   K split [0,384)+[384,512) merged by one fadd; epilogue single-rounded.
// Structure/protocol unchanged from r12: 256 blocks = 128 rec + 128 ff,
// 8 waves x 64 lanes (lane=row, wave=hidden unit j), no-reuse tagged ring
// (tag24|mask8), 2 barriers/step, ff spkb8 history, k_prepT/k_xw/k_c3/
// k_scan/k_out unchanged.
// ---------------------------------------------------------------------------

typedef unsigned int       u32;
typedef unsigned short     u16;
typedef unsigned long long u64;
typedef unsigned char      u8;

#define TSTEPS 512
#define HIDDEN 512

// workspace layout (bytes).
//   [0,64Mi)   XW transposed (dead after k_rec; c3 [0,32Mi) + Mem [32Mi,64Mi))
//   [64,80Mi)  ring32 (no-reuse tagged spike ring, k_rec only)
//   [96,100Mi) spkb8 (ff spike history, bytes)
//   [104Mi..)  WT, WinT (unchanged)
#define XW_OFF    0ull
#define C3_OFF    0ull
#define MEM_OFF   33554432ull
#define RINGN_OFF 67108864ull
#define SPKB_OFF  100663296ull
#define WT_OFF    109051904ull
#define WINT_OFF  109314048ull
#define WS_NEED   (134742016ull + 4096ull)

// ---------------------------------------------------------------------------
__global__ __launch_bounds__(256) void k_prepT(
    const float* __restrict__ Win,
    const float* __restrict__ Wmu, const float* __restrict__ Wlv,
    float* __restrict__ WinT, float* __restrict__ WT)
{
  const int idx = blockIdx.x * 256 + threadIdx.x;
  if (idx < 65536) {
    const int k = idx >> 9, j = idx & 511;
    WinT[idx] = Win[j * 128 + k];
  } else {
    const int i2 = idx - 65536;
    const int k = i2 >> 7, j = i2 & 127;
    WT[i2] = (j < 64) ? Wmu[j * 512 + k] : Wlv[(j - 64) * 512 + k];
  }
}

// ---------------------------------------------------------------------------
// k_xw: unchanged GEMM, TRANSPOSED store: XWT[(t2*512 + j)*128 + n].
// ---------------------------------------------------------------------------
__global__ __launch_bounds__(256) void k_xw(
    const float* __restrict__ state, const float* __restrict__ target,
    const float* __restrict__ WinT, const float* __restrict__ b_in,
    float* __restrict__ XWT)
{
  __shared__ float xs[16][129];
  const int tid  = threadIdx.x;
  const int row0 = blockIdx.x * 16;

  for (int e = tid; e < 2048; e += 256) {
    int r = e >> 7, k = e & 127;
    xs[r][k] = (k < 64) ? state[(row0 + r) * 64 + k]
                        : target[(row0 + r) * 64 + k - 64];
  }
  __syncthreads();

  const int t2 = row0 >> 7;
  const int n0 = row0 & 127;

#pragma unroll
  for (int jh = 0; jh < 2; ++jh) {
    const int j = jh * 256 + tid;
    float acc[16];
#pragma unroll
    for (int r = 0; r < 16; ++r) acc[r] = 0.0f;
    for (int k = 0; k < 128; ++k) {
      const float wv = WinT[k * 512 + j];
#pragma unroll
      for (int r = 0; r < 16; ++r)
        acc[r] = __builtin_fmaf(xs[r][k], wv, acc[r]);
    }
    const float b = b_in[j];
    float* dst = XWT + ((u64)t2 * 512 + j) * 128 + n0;
#pragma unroll
    for (int r4 = 0; r4 < 4; ++r4) {
      float4 o;
      o.x = __fadd_rn(acc[r4 * 4 + 0], b);
      o.y = __fadd_rn(acc[r4 * 4 + 1], b);
      o.z = __fadd_rn(acc[r4 * 4 + 2], b);
      o.w = __fadd_rn(acc[r4 * 4 + 3], b);
      *(float4*)(dst + r4 * 4) = o;
    }
  }
}

// ---------------------------------------------------------------------------
// k_rec: grid 256 x 512 threads (8 waves, 2/SIMD, FORCED 1 block/CU via LDS).
// blockIdx < 128: REC; >= 128: FF. Block (role, cb, R): wave w -> hidden unit
// jj = 8cb+w (wave-uniform, scalarized), lane n -> row gn = R*64+n.
// Weights: s_load stream (SMEM pipe) of Wrow[k], wave-uniform.
// Spikes: per-lane bits in VGPRs from the MB LDS tile.
// MAC: v_bfe_i32 + v_and_b32 + v_add_f32 (3 VALU), ascending k, 384-split.
// ---------------------------------------------------------------------------
__global__ __launch_bounds__(512, 2) void k_rec(
    const float* __restrict__ XWT,
    const float* __restrict__ Wrec, const float* __restrict__ Wff,
    const float* __restrict__ alpha_rec, const float* __restrict__ beta_rec,
    const float* __restrict__ b_rec,
    const float* __restrict__ b_ff, const float* __restrict__ alpha_ff,
    const float* __restrict__ beta_ff,
    u32* __restrict__ ring32, u8* __restrict__ spkb8)
{
  __shared__ __align__(16) u8 MB[64][80];   // [row][c8 byte], pad 80 (5120 B)
  __shared__ __align__(8)  u8 SP[64][8];    // [row][wave] spike bytes (512 B)
  __shared__ float padlds[19328];           // 77312 B -> total 82944 B:
                                            // forces exactly 1 block/CU.

  const int tid  = threadIdx.x;
  const int w    = tid >> 6;          // wave 0..7  -> j-offset
  const int n    = tid & 63;          // lane       -> row within rowgroup
  const int bb   = blockIdx.x & 127;
  const bool isFF = (blockIdx.x >= 128);
  const int cb   = bb >> 1;           // j-octet 0..63
  const int R    = bb & 1;            // rowgroup
  const int wrf  = __builtin_amdgcn_readfirstlane(w);
  const int jj   = cb * 8 + wrf;      // hidden unit (scalar/SGPR)
  const int gn   = R * 64 + n;        // global batch row

  // wave-uniform weight row base (scalar pointer -> s_load stream in MAC)
  const float* __restrict__ Wrow = (isFF ? Wff : Wrec) + (u64)jj * 512;

  const float coA = isFF ? alpha_ff[jj] : alpha_rec[jj];
  const float coB = isFF ? beta_ff[jj]  : beta_rec[jj];
  const float coC = isFF ? b_ff[jj]     : b_rec[jj];

  // keep the co-residency pad alive (never read back; one-time cost)
  ((volatile float*)padlds)[tid] = coC;

  float syn = 0.f, mem = 0.f, spk = 0.f, xw = 0.f;

#pragma unroll 1
  for (int i = 0; i < TSTEPS; ++i) {
    if (!isFF && !(i & 1))
      xw = XWT[((u64)(i >> 1) * 512 + jj) * 128 + gn];

    const int slot  = isFF ? i : (i - 1);
    const u32 expct = isFF ? (u32)(i + 1) : (u32)i;

    if (expct) {
      // poll 8 tagged words: c8 = 8w..8w+7, own row gn (coalesced per instr)
      const u32* src = ring32 + ((u64)slot * 64 + 8 * w) * 128 + gn;
      u32 vv[8];
      for (;;) {
        u32 bad = 0;
#pragma unroll
        for (int s = 0; s < 8; ++s) {
          vv[s] = __hip_atomic_load(src + s * 128, __ATOMIC_RELAXED,
                                    __HIP_MEMORY_SCOPE_AGENT);
          bad |= (vv[s] >> 8) ^ expct;
        }
        if (__all(bad == 0)) break;
        __builtin_amdgcn_s_sleep(1);
      }
      u64 mb = 0;
#pragma unroll
      for (int s = 0; s < 8; ++s) mb |= (u64)(vv[s] & 0xFFu) << (8 * s);
      *(u64*)&MB[n][8 * w] = mb;
    }
    __syncthreads();  // bar1: MB complete (prev-iter MAC reads fenced by bar2)

    float SA = 0.f;
    if (expct) {
      // own row's 512 spike bits: 64 bytes -> 16 VGPRs
      const uint4* bq = (const uint4*)&MB[n][0];
      const uint4 q0 = bq[0], q1 = bq[1], q2 = bq[2], q3 = bq[3];
      const u32 bw[16] = { q0.x, q0.y, q0.z, q0.w, q1.x, q1.y, q1.z, q1.w,
                           q2.x, q2.y, q2.z, q2.w, q3.x, q3.y, q3.z, q3.w };
      float aA = 0.f, aB = 0.f;
      // BLAS-faithful: ascending k, chunk split at 384, merged by one fadd.
      // Per k: bfe_i32 (0/-1 mask) + and with scalar weight + fadd.
#pragma unroll
      for (int kb = 0; kb < 12; ++kb) {
        const u32 word = bw[kb];
#pragma unroll
        for (int t = 0; t < 32; ++t) {
          const int m = (int)(word << (31 - t)) >> 31;            // 0 / -1
          const float ws =
              __int_as_float(m & __float_as_int(Wrow[kb * 32 + t]));
          aA = __fadd_rn(aA, ws);
        }
      }
#pragma unroll
      for (int kb = 12; kb < 16; ++kb) {
        const u32 word = bw[kb];
#pragma unroll
        for (int t = 0; t < 32; ++t) {
          const int m = (int)(word << (31 - t)) >> 31;
          const float ws =
              __int_as_float(m & __float_as_int(Wrow[kb * 32 + t]));
          aB = __fadd_rn(aB, ws);
        }
      }
      SA = __fadd_rn(aA, aB);
    }

    // epilogue (single-rounded, identical op sequence to r10..r12)
    const float cur = isFF ? __fadd_rn(SA, coC)
                           : __fadd_rn(__fadd_rn(xw, SA), coC);
    syn = __fadd_rn(__fmul_rn(coA, syn), cur);
    mem = __fsub_rn(__fadd_rn(__fmul_rn(coB, mem), syn), spk);
    spk = (mem > 1.0f) ? 1.0f : 0.0f;
    SP[n][w] = (u8)(spk != 0.f);

    __syncthreads();  // bar2: SP complete; also fences MB reuse next iter

    if (w == 0) {
      const u64 sv  = *(const u64*)&SP[n][0];
      const u32 lo4 = ((u32)sv         * 0x01020408u) >> 24;  // bits w=0..3
      const u32 hi4 = ((u32)(sv >> 32) * 0x01020408u) >> 24;  // bits w=4..7
      const u32 mask = lo4 | (hi4 << 4);
      if (!isFF) {
        __hip_atomic_store(ring32 + ((u64)i * 64 + cb) * 128 + gn,
                           ((u32)(i + 1) << 8) | mask,
                           __ATOMIC_RELAXED, __HIP_MEMORY_SCOPE_AGENT);
      } else {
        spkb8[((u64)i * 64 + cb) * 128 + gn] = (u8)mask;
      }
    }
  }
}

// ---------------------------------------------------------------------------
// k_c3: spk_f history (bytes, c8-major) @ W_mu/W_lv readout, + bias.
// ---------------------------------------------------------------------------
__global__ __launch_bounds__(256) void k_c3(
    const u8* __restrict__ spkb8, const float* __restrict__ WT,
    const float* __restrict__ bmu, const float* __restrict__ blv,
    float* __restrict__ c3)
{
  __shared__ __align__(8) u8 Bc[64][40];  // [c8][n-local 32, pad 40]
  const int tid   = threadIdx.x;
  const int rows0 = blockIdx.x * 32;
  const int t     = rows0 >> 7;
  const int n0    = rows0 & 127;

  {
    const int c8 = tid >> 2, g = tid & 3;
    const u64 vv = *(const u64*)(spkb8 + ((u64)t * 64 + c8) * 128 + n0 + 8 * g);
    *(u64*)&Bc[c8][8 * g] = vv;
  }
  __syncthreads();

  const int j  = tid & 127;
  const int rh = tid >> 7;
  const float bias = (j < 64) ? bmu[j] : blv[j - 64];

  float accA[16], accB[16];
#pragma unroll
  for (int r = 0; r < 16; ++r) { accA[r] = 0.f; accB[r] = 0.f; }

  for (int m = 0; m < 48; ++m) {   // k = 8m+kk < 384
    u32 w32[4];
#pragma unroll
    for (int q = 0; q < 4; ++q) w32[q] = *(const u32*)&Bc[m][rh * 16 + 4 * q];
    const float* wpp = WT + (m * 8) * 128 + j;
#pragma unroll
    for (int kk = 0; kk < 8; ++kk) {
      const float wvv = wpp[kk * 128];
#pragma unroll
      for (int r = 0; r < 16; ++r) {
        const float b = (float)((w32[r >> 2] >> (((r & 3) << 3) + kk)) & 1u);
        accA[r] = __builtin_fmaf(b, wvv, accA[r]);
      }
    }
  }
  for (int m = 48; m < 64; ++m) {  // k >= 384
    u32 w32[4];
#pragma unroll
    for (int q = 0; q < 4; ++q) w32[q] = *(const u32*)&Bc[m][rh * 16 + 4 * q];
    const float* wpp = WT + (m * 8) * 128 + j;
#pragma unroll
    for (int kk = 0; kk < 8; ++kk) {
      const float wvv = wpp[kk * 128];
#pragma unroll
      for (int r = 0; r < 16; ++r) {
        const float b = (float)((w32[r >> 2] >> (((r & 3) << 3) + kk)) & 1u);
        accB[r] = __builtin_fmaf(b, wvv, accB[r]);
      }
    }
  }

#pragma unroll
  for (int r = 0; r < 16; ++r)
    c3[(u64)(rows0 + rh * 16 + r) * 128 + j] =
        __fadd_rn(__fadd_rn(accA[r], accB[r]), bias);
}

// ---------------------------------------------------------------------------
__global__ __launch_bounds__(256) void k_scan(
    const float* __restrict__ c3,
    const float* __restrict__ beta_mu, const float* __restrict__ beta_lv,
    float* __restrict__ Mem)
{
  const int tid = blockIdx.x * 256 + threadIdx.x;
  const int n = tid >> 7, ap = tid & 127;
  const float beta = (ap < 64) ? beta_mu[ap] : beta_lv[ap - 64];
  const float* src = c3 + n * 128 + ap;
  float* dst = Mem + n * 128 + ap;
  float mem = 0.0f;
  for (int t = 0; t < 512; ++t) {
    mem = __fadd_rn(__fmul_rn(beta, mem), src[(u64)t * 16384]);
    dst[(u64)t * 16384] = mem;
  }
}

// ---------------------------------------------------------------------------
__global__ __launch_bounds__(256) void k_out(
    const float* __restrict__ Mem,
    const float* __restrict__ Wmu_out, const float* __restrict__ Wlv_out,
    float* __restrict__ out)
{
  const int tid = blockIdx.x * 256 + threadIdx.x;
  const int a = tid & 7;
  const int n = (tid >> 3) & 127;
  const int t = (tid >> 10) & 255;
  const int kind = tid >> 18;
  const float* wv = ((kind == 0) ? Wmu_out : Wlv_out) + a * 64;
  const float* s0 = Mem + ((u64)(2 * t) * 128 + n) * 128 + kind * 64;
  const float* s1 = Mem + ((u64)(2 * t + 1) * 128 + n) * 128 + kind * 64;
  float mu0 = 0.0f, mu1 = 0.0f;
#pragma unroll 8
  for (int q = 0; q < 64; ++q) mu0 = __builtin_fmaf(s0[q], wv[q], mu0);
#pragma unroll 8
  for (int q = 0; q < 64; ++q) mu1 = __builtin_fmaf(s1[q], wv[q], mu1);
  out[tid] = __fmul_rn(__fadd_rn(mu0, mu1), 0.5f);
}

// ---------------------------------------------------------------------------
extern "C" void kernel_launch(void* const* d_in, const int* in_sizes, int n_in,
                              void* d_out, int out_size, void* d_ws, size_t ws_size,
                              hipStream_t stream) {
  (void)in_sizes; (void)n_in; (void)out_size;
  if (ws_size < WS_NEED) return;

  const float* state     = (const float*)d_in[0];
  const float* target    = (const float*)d_in[1];
  const float* W_rec_in  = (const float*)d_in[2];
  const float* b_rec_in  = (const float*)d_in[3];
  const float* W_rec     = (const float*)d_in[4];
  const float* b_rec     = (const float*)d_in[5];
  const float* alpha_rec = (const float*)d_in[6];
  const float* beta_rec  = (const float*)d_in[7];
  const float* W_ff_in   = (const float*)d_in[8];
  const float* b_ff_in   = (const float*)d_in[9];
  const float* alpha_ff  = (const float*)d_in[10];
  const float* beta_ff   = (const float*)d_in[11];
  const float* W_mu_in   = (const float*)d_in[12];
  const float* b_mu_in   = (const float*)d_in[13];
  const float* beta_mu   = (const float*)d_in[14];
  const float* W_mu_out  = (const float*)d_in[15];
  const float* W_lv_in   = (const float*)d_in[16];
  const float* b_lv_in   = (const float*)d_in[17];
  const float* beta_lv   = (const float*)d_in[18];
  const float* W_lv_out  = (const float*)d_in[19];

  char* ws = (char*)d_ws;
  float* XWT   = (float*)(ws + XW_OFF);
  float* c3    = (float*)(ws + C3_OFF);
  float* Mem   = (float*)(ws + MEM_OFF);
  u32*   ring32= (u32*)  (ws + RINGN_OFF);
  u8*    spkb8 = (u8*)   (ws + SPKB_OFF);
  float* WT    = (float*)(ws + WT_OFF);
  float* WinT  = (float*)(ws + WINT_OFF);

  hipLaunchKernelGGL(k_prepT, dim3(512), dim3(256), 0, stream,
                     W_rec_in, W_mu_in, W_lv_in, WinT, WT);
  hipLaunchKernelGGL(k_xw, dim3(2048), dim3(256), 0, stream,
                     state, target, WinT, b_rec_in, XWT);
  hipLaunchKernelGGL(k_rec, dim3(256), dim3(512), 0, stream,
                     XWT, W_rec, W_ff_in,
                     alpha_rec, beta_rec, b_rec,
                     b_ff_in, alpha_ff, beta_ff, ring32, spkb8);
  hipLaunchKernelGGL(k_c3, dim3(2048), dim3(256), 0, stream,
                     spkb8, WT, b_mu_in, b_lv_in, c3);
  hipLaunchKernelGGL(k_scan, dim3(64), dim3(256), 0, stream,
                     c3, beta_mu, beta_lv, Mem);
  hipLaunchKernelGGL(k_out, dim3(2048), dim3(256), 0, stream,
                     Mem, W_mu_out, W_lv_out, (float*)d_out);
}